// Round 10
// baseline (839.348 us; speedup 1.0000x reference)
//
#include <hip/hip_runtime.h>
#include <math.h>

// DEQ fixed-point via Broyden. B=256, D=2048, T=12.
// R22: SELF-CONSUMING fusion at exact co-residency capacity. R17's failure
// was grid 768 > capacity 512: spin-waiting consumer blocks occupied CUs
// before producers ran. Fix: grid = 512 blocks x 512 thr = EXACTLY 2/CU x
// 256 CU (64KB LDS union, launch_bounds(512,4) caps VGPR<=128) -> all blocks
// co-resident. Every block does its R16 gemm tile first (tid<256 active),
// signals flag, then blocks 0..255 CONTINUE into broyden row b=bid (R17's
// correctness-validated consumer code verbatim; state/G/c prefetch overlaps
// the wait). No block waits before finishing producer work -> no inversion.
// 28 -> 15 dispatches; attacks launch-gap fixed cost that R13-R21 kernel
// tuning can't reach (R16 tile config is a measured local optimum: 128-row
// R13 and 32-row R20/21 both lose ~10us).
// R16/R15: quad-buffered gemm, vmcnt(8/4/0) + raw s_barrier; fast_tanh.
// R14: wave-0-synchronous fp64 solve. R13: 4 y partial planes; loop gemm
// bf16 A K=2048 + fp16 y; k0 gemm hi|lo A K=4096 + fp32 y. Gram-space
// Broyden, bf16 g-planes.

#define DD 2048
#define KA 4096            // Axx (k0) stride: [hi|lo]
#define KW 2048
#define BB 256
#define BD (BB * DD)
#define TT 12
#define NKS 4              // k-slices (partial y planes)

// state layout (floats, per row, stride 1024)
#define ST_S   0           // 169
#define ST_A   169         // 12*13
#define ST_B   325         // 12*13
#define ST_PHI 481         // 13
#define ST_XI  494         // 13
#define ST_XSN 507         // 13*13
#define ST_SZ  1024

typedef unsigned short ushort_t;
typedef _Float16 half_t;
typedef __attribute__((ext_vector_type(8))) short short8;
typedef __attribute__((ext_vector_type(4))) float floatx4;
typedef __attribute__((ext_vector_type(4))) _Float16 half4;

__device__ __forceinline__ ushort_t f2bf(float f) {
    unsigned int u = __float_as_uint(f);
    unsigned int r = (u + 0x7FFFu + ((u >> 16) & 1u)) >> 16;
    return (ushort_t)r;
}
__device__ __forceinline__ float bf2f(ushort_t h) {
    return __uint_as_float(((unsigned int)h) << 16);
}
__device__ __forceinline__ float fast_tanh(float x) {
    float e = __expf(2.f * x);
    return 1.f - 2.f / (e + 1.f);
}
__device__ __forceinline__ void gload_lds16(const void* g, void* l) {
    __builtin_amdgcn_global_load_lds(
        (const __attribute__((address_space(1))) unsigned int*)g,
        (__attribute__((address_space(3))) unsigned int*)l, 16, 0, 0);
}
__device__ __forceinline__ float wave_red(float v) {
#pragma unroll
    for (int off = 32; off > 0; off >>= 1) v += __shfl_down(v, off, 64);
    return v;
}
// in-wave LDS fence (wave-synchronous solve): all prior ds ops complete.
#define WS() do { asm volatile("s_waitcnt lgkmcnt(0)" ::: "memory"); \
                  __builtin_amdgcn_wave_barrier(); } while (0)

// shared-memory union: gemm staging (64 KB) vs broyden solve scratch (~3 KB)
union SharedU {
    struct { ushort_t As[4][4096]; ushort_t Bs[4][4096]; } g;
    struct {
        float red[8][16];
        float dots[14];
        float Sl[169], Al[156], Bl[156], PHl[13], XIl[13];
        float newA[14], newB[14], nphi[14];
        double dyv[13], dxtu[12], dvdg[12], dcgx[13], dden[1];
    } b;
};

// ---------------- prep: W/U -> bf16 [n][k] planes; Axx hi|lo; zero state+flags ----------------
__global__ __launch_bounds__(256)
void prep(const float* __restrict__ W, const float* __restrict__ U,
          ushort_t* __restrict__ Wt, ushort_t* __restrict__ Ut,
          const float* __restrict__ xin, ushort_t* __restrict__ Axx,
          float* __restrict__ stbase) {
    __shared__ ushort_t Hs[64][65];
    const int bid = blockIdx.x;
    const int tid = threadIdx.x;
    if (bid < 2048) {
        const int bz = bid >> 10, by = (bid >> 5) & 31, bx = bid & 31;
        const float* src = bz ? U : W;
        ushort_t* dst = bz ? Ut : Wt;
        const int k0 = by * 64, n0 = bx * 64;
        const int r = tid >> 4, c4 = (tid & 15) * 4;
#pragma unroll
        for (int i = 0; i < 4; ++i) {
            int kr = r + i * 16;
            float4 w = *(const float4*)(src + (size_t)(k0 + kr) * DD + n0 + c4);
            Hs[kr][c4 + 0] = f2bf(w.x); Hs[kr][c4 + 1] = f2bf(w.y);
            Hs[kr][c4 + 2] = f2bf(w.z); Hs[kr][c4 + 3] = f2bf(w.w);
        }
        __syncthreads();
#pragma unroll
        for (int i = 0; i < 4; ++i) {
            int nr = r + i * 16;
            ushort4 hv = { Hs[c4+0][nr], Hs[c4+1][nr], Hs[c4+2][nr], Hs[c4+3][nr] };
            *(ushort4*)(dst + (size_t)(n0 + nr) * KW + (size_t)(k0 + c4)) = hv;
        }
    } else {
        const int i4 = (bid - 2048) * 256 + tid;
        const int idx = i4 * 4;
        const int m = idx >> 11, col = idx & 2047;
        float4 xv = ((const float4*)xin)[i4];
        float a[4] = {xv.x, xv.y, xv.z, xv.w};
        ushort_t hh[4], ll[4];
#pragma unroll
        for (int j = 0; j < 4; ++j) { hh[j] = f2bf(a[j]); ll[j] = f2bf(a[j] - bf2f(hh[j])); }
        ushort4 h = {hh[0],hh[1],hh[2],hh[3]}, l = {ll[0],ll[1],ll[2],ll[3]};
        size_t ab = (size_t)m * KA + col;
        *(ushort4*)(Axx + ab) = h; *(ushort4*)(Axx + ab + DD) = l;
        if (i4 < 65548) {            // state 262144 + scal 32 + flags 16 (as floats)
            float4 z = {0.f, 0.f, 0.f, 0.f};
            ((float4*)stbase)[i4] = z;
        }
    }
}

// ---------------- gemm producer part (all 512 blocks) ----------------
// R16 geometry: bid -> (n = bid&31, mt = (bid>>5)&3, ks = bid>>7); 4 active
// waves (tid<256), wave 32x32; quad-buffered 64x64 chunks, counted vmcnt +
// raw s_barrier. Waves 4..7 idle through the barriers (validated in R17).
template<int LDA, int KSLICE, int NIT, int BMOD, typename YT>
__device__ __forceinline__ void gemm_part(const ushort_t* __restrict__ A,
                                          const ushort_t* __restrict__ Bt,
                                          YT* __restrict__ y, SharedU& sh) {
    ushort_t (*As)[4096] = sh.g.As;
    ushort_t (*Bs)[4096] = sh.g.Bs;
    const int tid = threadIdx.x;
    const bool act = tid < 256;
    const int bid = blockIdx.x;
    const int bn = (bid & 31) * 64;
    const int mt = (bid >> 5) & 3;
    const int ks = bid >> 7;
    const int lane = tid & 63, w = tid >> 6;
    const int waveM = (w >> 1) & 1, waveN = w & 1;

    const int srow = (tid >> 3) & 31;
    const int sg = (tid & 7) ^ (srow & 7);
    const ushort_t* Ag = A  + (size_t)(mt * 64 + srow) * LDA + ks * KSLICE + sg * 8;
    const ushort_t* Bg = Bt + (size_t)(bn + srow) * KW + (ks & BMOD) * KSLICE + sg * 8;
    const size_t rsA = (size_t)32 * LDA;
    const size_t rsB = (size_t)32 * KW;

    const int q = lane >> 4, rl = lane & 15;
    int offA[2][2], offB[2][2];
#pragma unroll
    for (int kk = 0; kk < 2; ++kk) {
        int j = kk * 4 + q;
#pragma unroll
        for (int mi = 0; mi < 2; ++mi) {
            int m = waveM * 32 + mi * 16 + rl;
            offA[kk][mi] = (m * 8 + (j ^ (m & 7))) * 8;
        }
#pragma unroll
        for (int ni = 0; ni < 2; ++ni) {
            int n = waveN * 32 + ni * 16 + rl;
            offB[kk][ni] = (n * 8 + (j ^ (n & 7))) * 8;
        }
    }

    floatx4 acc[2][2];
#pragma unroll
    for (int mi = 0; mi < 2; ++mi)
#pragma unroll
        for (int ni = 0; ni < 2; ++ni) acc[mi][ni] = (floatx4){0.f,0.f,0.f,0.f};

    if (act) {
#pragma unroll
        for (int t = 0; t < 3; ++t) {
            gload_lds16(Ag,       As[t] + tid * 8);
            gload_lds16(Ag + rsA, As[t] + (256 + tid) * 8);
            gload_lds16(Bg,       Bs[t] + tid * 8);
            gload_lds16(Bg + rsB, Bs[t] + (256 + tid) * 8);
            Ag += 64; Bg += 64;
        }
    }

#pragma unroll
    for (int it = 0; it < NIT; ++it) {
        const int rem = NIT - 1 - it;
        if (rem >= 2)      asm volatile("s_waitcnt vmcnt(8)" ::: "memory");
        else if (rem == 1) asm volatile("s_waitcnt vmcnt(4)" ::: "memory");
        else               asm volatile("s_waitcnt vmcnt(0)" ::: "memory");
        __builtin_amdgcn_s_barrier();
        if (it + 3 < NIT) {
            if (act) {
                const int nb4 = (it + 3) & 3;
                gload_lds16(Ag,       As[nb4] + tid * 8);
                gload_lds16(Ag + rsA, As[nb4] + (256 + tid) * 8);
                gload_lds16(Bg,       Bs[nb4] + tid * 8);
                gload_lds16(Bg + rsB, Bs[nb4] + (256 + tid) * 8);
                Ag += 64; Bg += 64;
            }
        }
        if (act) {
            const ushort_t* Ab = As[it & 3];
            const ushort_t* Bb = Bs[it & 3];
#pragma unroll
            for (int kk = 0; kk < 2; ++kk) {
                short8 b0 = *(const short8*)(Bb + offB[kk][0]);
                short8 b1 = *(const short8*)(Bb + offB[kk][1]);
#pragma unroll
                for (int mi = 0; mi < 2; ++mi) {
                    short8 a = *(const short8*)(Ab + offA[kk][mi]);
                    acc[mi][0] = __builtin_amdgcn_mfma_f32_16x16x32_bf16(a, b0, acc[mi][0], 0, 0, 0);
                    acc[mi][1] = __builtin_amdgcn_mfma_f32_16x16x32_bf16(a, b1, acc[mi][1], 0, 0, 0);
                }
            }
        }
    }

    if (act) {
        YT* yp = y + (size_t)ks * BD;
        const int mb = mt * 64 + waveM * 32 + q * 4;
        const int nb = bn + waveN * 32 + rl;
#pragma unroll
        for (int mi = 0; mi < 2; ++mi)
#pragma unroll
            for (int r = 0; r < 4; ++r) {
                yp[(size_t)(mb + mi * 16 + r) * DD + nb]      = (YT)acc[mi][0][r];
                yp[(size_t)(mb + mi * 16 + r) * DD + nb + 16] = (YT)acc[mi][1][r];
            }
    }
}

// ---------------- flag signal / wait (R17-validated) ----------------
__device__ __forceinline__ void signal_flag(unsigned int* flagp) {
    __syncthreads();           // all waves' y stores retired (vmcnt drained)
    if (threadIdx.x == 0) {
        __threadfence();       // release: y visible device-wide
        __hip_atomic_fetch_add(flagp, 1u, __ATOMIC_RELEASE, __HIP_MEMORY_SCOPE_AGENT);
    }
}
__device__ __forceinline__ void wait_flag(unsigned int* flagp) {
    __syncthreads();           // prefetch LDS staging complete
    if (threadIdx.x == 0) {
        while (__hip_atomic_load(flagp, __ATOMIC_RELAXED, __HIP_MEMORY_SCOPE_AGENT) < 512u)
            __builtin_amdgcn_s_sleep(2);
        __threadfence();       // acquire: invalidate stale caches before y reads
    }
    __syncthreads();
}

// ---------------- fused gemm + (epi0 | broyden), self-consuming ----------------
template<int LDA, int KSLICE, int NIT, int BMOD, typename YT, bool K0>
__global__ __launch_bounds__(512, 4)
void fused(const ushort_t* __restrict__ A, const ushort_t* __restrict__ Bt,
           YT* __restrict__ y, const float* __restrict__ bias,
           float* __restrict__ c, ushort_t* __restrict__ gxp,
           ushort_t* __restrict__ Azz, float* __restrict__ state,
           float* __restrict__ scal, unsigned int* __restrict__ flagp, int k)
{
    __shared__ SharedU sh;
    const int bid = blockIdx.x;
    const int tid = threadIdx.x;

    // producer: every block computes its gemm tile first
    gemm_part<LDA, KSLICE, NIT, BMOD, YT>(A, Bt, y, sh);
    signal_flag(flagp);
    if (bid >= BB) return;     // blocks 256..511: pure producers

    const int b = bid;
    const int lane = tid & 63, w = tid >> 6;
    const int col = tid * 4;
    const size_t base = (size_t)b * DD + col;
    float* stb = state + (size_t)b * ST_SZ;

    if (K0) {
        // ---- epi0 consumer: prefetch bias, wait, then c/g0/state init ----
        float4 cc = *(const float4*)(bias + col);
        wait_flag(flagp);
#pragma unroll
        for (int s = 0; s < NKS; ++s) {
            float4 v = *(const float4*)((const float*)y + (size_t)s * BD + base);
            cc.x += v.x; cc.y += v.y; cc.z += v.z; cc.w += v.w;
        }
        *(float4*)(c + base) = cc;
        float4 g = { fast_tanh(cc.x), fast_tanh(cc.y), fast_tanh(cc.z), fast_tanh(cc.w) };
        ushort4 gs = { f2bf(g.x), f2bf(g.y), f2bf(g.z), f2bf(g.w) };
        *(ushort4*)(gxp + base) = gs;
        *(ushort4*)(Azz + base) = gs;     // x1 = g0, single bf16 plane

        float pd = g.x*g.x + g.y*g.y + g.z*g.z + g.w*g.w;
        pd = wave_red(pd);
        if (lane == 0) sh.b.red[w][0] = pd;
        __syncthreads();
        if (tid == 0) {
            float t = 0.f;
#pragma unroll
            for (int w2 = 0; w2 < 8; ++w2) t += sh.b.red[w2][0];
            stb[ST_S + 0]   = t;
            stb[ST_PHI + 0] = 1.f;
            stb[ST_XI + 0]  = 1.f;
            atomicAdd(&scal[0], t);
        }
        return;
    }

    // ---- broyden consumer: prefetch state/G/c (y-independent), wait, solve ----
    const int p = k - 1;

    for (int i = tid; i < 169; i += 512) sh.b.Sl[i] = stb[ST_S + i];
    for (int i = tid; i < 156; i += 512) { sh.b.Al[i] = stb[ST_A + i]; sh.b.Bl[i] = stb[ST_B + i]; }
    if (tid < 13) { sh.b.PHl[tid] = stb[ST_PHI + tid]; sh.b.XIl[tid] = stb[ST_XI + tid]; }

    float4 G[12];
#pragma unroll
    for (int j = 0; j < 12; ++j)
        if (j < k) {
            ushort4 gu = *(const ushort4*)(gxp + (size_t)j * BD + base);
            G[j] = (float4){ bf2f(gu.x), bf2f(gu.y), bf2f(gu.z), bf2f(gu.w) };
        }
    float4 pre = *(const float4*)(c + base);

    wait_flag(flagp);   // includes the syncthreads that publishes LDS staging

    const half_t* yh = (const half_t*)y;
#pragma unroll
    for (int s = 0; s < NKS; ++s) {
        half4 v = *(const half4*)(yh + (size_t)s * BD + base);
        pre.x += (float)v.x; pre.y += (float)v.y;
        pre.z += (float)v.z; pre.w += (float)v.w;
    }

    float4 x = {0.f, 0.f, 0.f, 0.f};
#pragma unroll
    for (int j = 0; j < 12; ++j)
        if (j < k) {
            float xc = sh.b.XIl[j];
            x.x = fmaf(xc, G[j].x, x.x); x.y = fmaf(xc, G[j].y, x.y);
            x.z = fmaf(xc, G[j].z, x.z); x.w = fmaf(xc, G[j].w, x.w);
        }
    float4 gk = { fast_tanh(pre.x) - x.x, fast_tanh(pre.y) - x.y,
                  fast_tanh(pre.z) - x.z, fast_tanh(pre.w) - x.w };

    // g_k plane store: independent of solve, overlaps reductions
    {
        ushort4 gs = { f2bf(gk.x), f2bf(gk.y), f2bf(gk.z), f2bf(gk.w) };
        *(ushort4*)(gxp + (size_t)k * BD + base) = gs;
    }

#pragma unroll
    for (int j = 0; j < 12; ++j)
        if (j < k) {
            float pd = G[j].x*gk.x + G[j].y*gk.y + G[j].z*gk.z + G[j].w*gk.w;
            pd = wave_red(pd);
            if (lane == 0) sh.b.red[w][j] = pd;
        }
    {
        float pdk = gk.x*gk.x + gk.y*gk.y + gk.z*gk.z + gk.w*gk.w;
        pdk = wave_red(pdk);
        if (lane == 0) sh.b.red[w][k] = pdk;
    }
    __syncthreads();

    if (w == 0) {
        if (lane <= k) {
            float s = 0.f;
#pragma unroll
            for (int w2 = 0; w2 < 8; ++w2) s += sh.b.red[w2][lane];
            sh.b.dots[lane] = s;
            if (lane == k) atomicAdd(&scal[k], s);
        }
        WS();
        if (lane < k) {
            double s = 0.0;
            for (int j = 0; j < k; ++j) s += (double)sh.b.Sl[lane*13 + j] * (double)sh.b.PHl[j];
            sh.b.dyv[lane] = s;
        }
        WS();
        if (lane < p) {
            double sx = 0.0, sv = 0.0;
            for (int j = 0; j < k; ++j) {
                sx += (double)sh.b.Al[lane*13 + j] * sh.b.dyv[j];
                sv += (double)sh.b.Bl[lane*13 + j] * ((double)sh.b.dots[j] - (double)sh.b.Sl[j*13 + (k-1)]);
            }
            sh.b.dxtu[lane] = sx; sh.b.dvdg[lane] = sv;
        }
        WS();
        if (lane < k) {
            double s = -(double)sh.b.PHl[lane];
            for (int t = 0; t < p; ++t) s += sh.b.dxtu[t] * (double)sh.b.Bl[t*13 + lane];
            sh.b.newB[lane] = (float)s;
        }
        WS();
        if (lane == 0) {
            double s = 0.0;
            for (int j = 0; j < k; ++j)
                s += (double)sh.b.newB[j] * ((double)sh.b.dots[j] - (double)sh.b.Sl[j*13 + (k-1)]);
            sh.b.dden[0] = s;
        }
        if (lane >= 32 && lane < 32 + p) {
            int t = lane - 32;
            double s = 0.0;
            for (int j = 0; j < k; ++j) s += (double)sh.b.Bl[t*13 + j] * (double)sh.b.dots[j];
            sh.b.dcgx[t] = s;
        }
        if (lane == 63) {
            double s = 0.0;
            for (int j = 0; j < k; ++j) s += (double)sh.b.newB[j] * (double)sh.b.dots[j];
            sh.b.dcgx[p] = s;
        }
        WS();
        if (lane <= k) {
            double s = (double)((lane < 13) ? sh.b.PHl[lane] : 0.f);
            if (lane == k)     s += 1.0;
            if (lane == k - 1) s -= 1.0;
            for (int t = 0; t < p; ++t) s -= sh.b.dvdg[t] * (double)sh.b.Al[t*13 + lane];
            sh.b.newA[lane] = (float)(s / sh.b.dden[0]);
        }
        WS();
        if (lane <= k) {
            double s = (lane == k) ? 1.0 : 0.0;
            for (int t = 0; t < p; ++t) s -= sh.b.dcgx[t] * (double)sh.b.Al[t*13 + lane];
            s -= sh.b.dcgx[p] * (double)sh.b.newA[lane];
            sh.b.nphi[lane] = (float)s;
        }
        WS();
        if (lane <= k) {
            stb[ST_S + k*13 + lane] = sh.b.dots[lane];
            stb[ST_S + lane*13 + k] = sh.b.dots[lane];
            stb[ST_A + p*13 + lane] = sh.b.newA[lane];
            stb[ST_PHI + lane] = sh.b.nphi[lane];
            float xi_old = (lane < 13) ? sh.b.XIl[lane] : 0.f;
            stb[ST_XI + lane] = xi_old + sh.b.nphi[lane];
        }
        if (lane < k) stb[ST_B + p*13 + lane] = sh.b.newB[lane];
        if (lane < 13) stb[ST_XSN + k*13 + lane] = sh.b.XIl[lane];   // coeffs of x_k
    }
    __syncthreads();

    if (k < TT) {   // x_{k+1}/Azz dead at k=TT
        float4 xn = x;
#pragma unroll
        for (int j = 0; j < 12; ++j)
            if (j < k) {
                float fc = sh.b.nphi[j];
                xn.x = fmaf(fc, G[j].x, xn.x); xn.y = fmaf(fc, G[j].y, xn.y);
                xn.z = fmaf(fc, G[j].z, xn.z); xn.w = fmaf(fc, G[j].w, xn.w);
            }
        float fk = sh.b.nphi[k];
        xn.x = fmaf(fk, gk.x, xn.x); xn.y = fmaf(fk, gk.y, xn.y);
        xn.z = fmaf(fk, gk.z, xn.z); xn.w = fmaf(fk, gk.w, xn.w);

        ushort4 h = { f2bf(xn.x), f2bf(xn.y), f2bf(xn.z), f2bf(xn.w) };
        *(ushort4*)(Azz + base) = h;              // single bf16 plane
    }
}

// ---------------- final: argmin obj; out = x_bk + g_bk from bf16 planes ----------------
__global__ __launch_bounds__(256)
void final_out(const ushort_t* __restrict__ gxp, const float* __restrict__ state,
               const float* __restrict__ scal, float* __restrict__ out) {
    const int i4 = blockIdx.x * 256 + threadIdx.x;
    float best = scal[0];
    int bk = 0;
#pragma unroll
    for (int k = 1; k <= TT; ++k) {
        float o = scal[k];
        if (o < best) { best = o; bk = k; }
    }
    const size_t idx = (size_t)i4 * 4;
    const int m = (int)(idx >> 11);
    const float* cf = state + (size_t)m * ST_SZ + ST_XSN + bk * 13;
    ushort4 gb = *(const ushort4*)(gxp + (size_t)bk * BD + idx);
    float4 r = { bf2f(gb.x), bf2f(gb.y), bf2f(gb.z), bf2f(gb.w) };
    for (int j = 0; j < bk; ++j) {
        float c1 = cf[j];
        ushort4 gu = *(const ushort4*)(gxp + (size_t)j * BD + idx);
        r.x = fmaf(c1, bf2f(gu.x), r.x); r.y = fmaf(c1, bf2f(gu.y), r.y);
        r.z = fmaf(c1, bf2f(gu.z), r.z); r.w = fmaf(c1, bf2f(gu.w), r.w);
    }
    ((float4*)out)[i4] = r;
}

// ---------------- launch ----------------
extern "C" void kernel_launch(void* const* d_in, const int* in_sizes, int n_in,
                              void* d_out, int out_size, void* d_ws, size_t ws_size,
                              hipStream_t stream) {
    const float* xin  = (const float*)d_in[0];
    const float* W    = (const float*)d_in[2];
    const float* U    = (const float*)d_in[3];
    const float* bias = (const float*)d_in[4];
    float* out = (float*)d_out;

    float* ws = (float*)d_ws;
    float* c      = ws;                                   // 1 BD
    float* y      = ws + 1 * (size_t)BD;                  // 4 BD fp32 (k0) / fp16 (loop)
    ushort_t* gxp = (ushort_t*)(ws + 9 * (size_t)BD);     // 13 bf16 planes = 6.5 BD
    ushort_t* Axx = (ushort_t*)(ws + 16 * (size_t)BD);    // [256][4096] u16 = 1 BD
    ushort_t* Azz = (ushort_t*)(ws + 17 * (size_t)BD);    // [256][2048] u16 = 0.5 BD
    ushort_t* Wt  = (ushort_t*)(ws + 18 * (size_t)BD);    // 4 BD
    ushort_t* Ut  = (ushort_t*)(ws + 22 * (size_t)BD);    // 4 BD
    float* state  = ws + 26 * (size_t)BD;                 // 0.5 BD
    float* scal   = state + (size_t)BB * ST_SZ;           // 32 floats
    unsigned int* flags = (unsigned int*)(scal + 32);     // 16 uints, zeroed by prep

    prep<<<2560, 256, 0, stream>>>(W, U, Wt, Ut, xin, Axx, state);

    // k=0: hi|lo A (K=4096), fp32 y; fused with epi0 (self-consuming)
    fused<4096, 1024, 16, 1, float, true><<<512, 512, 0, stream>>>(
        Axx, Ut, y, bias, c, gxp, Azz, state, scal, flags + 0, 0);

    for (int k = 1; k <= TT; ++k) {
        // loop: single bf16 A (K=2048), fp16 y; fused with broyden
        fused<2048, 512, 8, 3, half_t, false><<<512, 512, 0, stream>>>(
            Azz, Wt, (half_t*)y, bias, c, gxp, Azz, state, scal, flags + k, k);
    }

    final_out<<<512, 256, 0, stream>>>(gxp, state, scal, out);
}

// Round 11
// 324.966 us; speedup vs baseline: 2.5829x; 2.5829x over previous
//
#include <hip/hip_runtime.h>
#include <math.h>

// DEQ fixed-point via Broyden. B=256, D=2048, T=12.
// R23: revert R22 fusion (839us; per-block release/acquire fences on
// XCD-incoherent L2 = cache-flush storms -- FETCH 16.5MB/dispatch, 450 GB/s.
// Cross-block dataflow MUST cross kernel boundaries: measured 4x now
// R5/R9/R17/R22). Base = R16 (325us best). New: k0 gemm ks-split 4->8
// (zero-redundancy split, unlike R21's mt-split): grid (32,4,8)=1024 blocks,
// NIT=8, DOUBLE-buffered 32KB LDS -> 4 blocks/CU true occupancy (vs 2).
// Cost: 8 fp32 y planes (+2.6us traffic). Loop gemm untouched (quad, NKS=4).
// Probe: does redundancy-free block-parallelism help latency-bound gemms?
// R16/R15: counted vmcnt + raw s_barrier; fast_tanh. R14: wave-0-synchronous
// fp64 solve. R13: loop gemm bf16 A K=2048 + fp16 y; k0 hi|lo A K=4096 +
// fp32 y. Gram-space Broyden, bf16 g-planes.

#define DD 2048
#define KA 4096            // Axx (k0) stride: [hi|lo]
#define KW 2048
#define BB 256
#define BD (BB * DD)
#define TT 12
#define NKS0 8             // k0 k-slices (fp32 y planes)
#define NKSL 4             // loop k-slices (fp16 y planes)

// state layout (floats, per row, stride 1024)
#define ST_S   0           // 169
#define ST_A   169         // 12*13
#define ST_B   325         // 12*13
#define ST_PHI 481         // 13
#define ST_XI  494         // 13
#define ST_XSN 507         // 13*13
#define ST_SZ  1024

typedef unsigned short ushort_t;
typedef _Float16 half_t;
typedef __attribute__((ext_vector_type(8))) short short8;
typedef __attribute__((ext_vector_type(4))) float floatx4;
typedef __attribute__((ext_vector_type(4))) _Float16 half4;

__device__ __forceinline__ ushort_t f2bf(float f) {
    unsigned int u = __float_as_uint(f);
    unsigned int r = (u + 0x7FFFu + ((u >> 16) & 1u)) >> 16;
    return (ushort_t)r;
}
__device__ __forceinline__ float bf2f(ushort_t h) {
    return __uint_as_float(((unsigned int)h) << 16);
}
__device__ __forceinline__ float fast_tanh(float x) {
    float e = __expf(2.f * x);
    return 1.f - 2.f / (e + 1.f);
}
__device__ __forceinline__ void gload_lds16(const void* g, void* l) {
    __builtin_amdgcn_global_load_lds(
        (const __attribute__((address_space(1))) unsigned int*)g,
        (__attribute__((address_space(3))) unsigned int*)l, 16, 0, 0);
}
__device__ __forceinline__ float wave_red(float v) {
#pragma unroll
    for (int off = 32; off > 0; off >>= 1) v += __shfl_down(v, off, 64);
    return v;
}
// in-wave LDS fence (wave-synchronous solve): all prior ds ops complete.
#define WS() do { asm volatile("s_waitcnt lgkmcnt(0)" ::: "memory"); \
                  __builtin_amdgcn_wave_barrier(); } while (0)

// ---------------- prep: W/U -> bf16 [n][k] planes; Axx hi|lo; zero state ----------------
__global__ __launch_bounds__(256)
void prep(const float* __restrict__ W, const float* __restrict__ U,
          ushort_t* __restrict__ Wt, ushort_t* __restrict__ Ut,
          const float* __restrict__ xin, ushort_t* __restrict__ Axx,
          float* __restrict__ stbase) {
    __shared__ ushort_t Hs[64][65];
    const int bid = blockIdx.x;
    const int tid = threadIdx.x;
    if (bid < 2048) {
        const int bz = bid >> 10, by = (bid >> 5) & 31, bx = bid & 31;
        const float* src = bz ? U : W;
        ushort_t* dst = bz ? Ut : Wt;
        const int k0 = by * 64, n0 = bx * 64;
        const int r = tid >> 4, c4 = (tid & 15) * 4;
#pragma unroll
        for (int i = 0; i < 4; ++i) {
            int kr = r + i * 16;
            float4 w = *(const float4*)(src + (size_t)(k0 + kr) * DD + n0 + c4);
            Hs[kr][c4 + 0] = f2bf(w.x); Hs[kr][c4 + 1] = f2bf(w.y);
            Hs[kr][c4 + 2] = f2bf(w.z); Hs[kr][c4 + 3] = f2bf(w.w);
        }
        __syncthreads();
#pragma unroll
        for (int i = 0; i < 4; ++i) {
            int nr = r + i * 16;
            ushort4 hv = { Hs[c4+0][nr], Hs[c4+1][nr], Hs[c4+2][nr], Hs[c4+3][nr] };
            *(ushort4*)(dst + (size_t)(n0 + nr) * KW + (size_t)(k0 + c4)) = hv;
        }
    } else {
        const int i4 = (bid - 2048) * 256 + tid;
        const int idx = i4 * 4;
        const int m = idx >> 11, col = idx & 2047;
        float4 xv = ((const float4*)xin)[i4];
        float a[4] = {xv.x, xv.y, xv.z, xv.w};
        ushort_t hh[4], ll[4];
#pragma unroll
        for (int j = 0; j < 4; ++j) { hh[j] = f2bf(a[j]); ll[j] = f2bf(a[j] - bf2f(hh[j])); }
        ushort4 h = {hh[0],hh[1],hh[2],hh[3]}, l = {ll[0],ll[1],ll[2],ll[3]};
        size_t ab = (size_t)m * KA + col;
        *(ushort4*)(Axx + ab) = h; *(ushort4*)(Axx + ab + DD) = l;
        if (i4 < 65544) {            // state 262144 + scal 32 floats
            float4 z = {0.f, 0.f, 0.f, 0.f};
            ((float4*)stbase)[i4] = z;
        }
    }
}

// ---------------- GEMM (templated on K geometry, buffering, y dtype) ----------------
// grid (32, 4, NKS): x = n-tile (64), y = m-tile (64 rows), z = ks.
// Linear bid = n + 32*mt + 128*ks -> XCD = n%8: all (mt,ks) of one n-tile
// co-XCD. 256 thr = 4 waves, wave 32x32. NBUF-buffered 64x64 A/B chunks
// (NBUF x 16KB LDS); prefetch distance NBUF-1, counted vmcnt + raw s_barrier.
// NBUF=4 (64KB, 2 blk/CU) for 512-block loop; NBUF=2 (32KB, 5 blk/CU) for
// the 1024-block k0 split -- intra-block pipelining traded for block TLP.
template<int LDA, int KSLICE, int NIT, int BMOD, int NBUF, typename YT>
__global__ __launch_bounds__(256)
void gemm_t(const ushort_t* __restrict__ A, const ushort_t* __restrict__ Bt,
            YT* __restrict__ y) {
    __shared__ ushort_t As[NBUF][64 * 64];
    __shared__ ushort_t Bs[NBUF][64 * 64];
    const int tid = threadIdx.x;
    const int lane = tid & 63, w = tid >> 6;
    const int bn = blockIdx.x * 64;
    const int mt = blockIdx.y;
    const int ks = blockIdx.z;
    const int waveM = w >> 1, waveN = w & 1;

    const int srow = tid >> 3;             // 0..31
    const int sg = (tid & 7) ^ (srow & 7);
    const ushort_t* Ag = A  + (size_t)(mt * 64 + srow) * LDA + ks * KSLICE + sg * 8;
    const ushort_t* Bg = Bt + (size_t)(bn + srow) * KW + (ks & BMOD) * KSLICE + sg * 8;
    const size_t rsA = (size_t)32 * LDA;
    const size_t rsB = (size_t)32 * KW;

    const int q = lane >> 4, rl = lane & 15;
    int offA[2][2], offB[2][2];
#pragma unroll
    for (int kk = 0; kk < 2; ++kk) {
        int j = kk * 4 + q;
#pragma unroll
        for (int mi = 0; mi < 2; ++mi) {
            int m = waveM * 32 + mi * 16 + rl;
            offA[kk][mi] = (m * 8 + (j ^ (m & 7))) * 8;
        }
#pragma unroll
        for (int ni = 0; ni < 2; ++ni) {
            int n = waveN * 32 + ni * 16 + rl;
            offB[kk][ni] = (n * 8 + (j ^ (n & 7))) * 8;
        }
    }

    floatx4 acc[2][2];
#pragma unroll
    for (int mi = 0; mi < 2; ++mi)
#pragma unroll
        for (int ni = 0; ni < 2; ++ni) acc[mi][ni] = (floatx4){0.f,0.f,0.f,0.f};

    // prologue: tiles 0..NBUF-2 in flight
#pragma unroll
    for (int t = 0; t < NBUF - 1; ++t) {
        gload_lds16(Ag,       As[t] + tid * 8);
        gload_lds16(Ag + rsA, As[t] + (256 + tid) * 8);
        gload_lds16(Bg,       Bs[t] + tid * 8);
        gload_lds16(Bg + rsB, Bs[t] + (256 + tid) * 8);
        Ag += 64; Bg += 64;
    }

#pragma unroll
    for (int it = 0; it < NIT; ++it) {
        // wait for tile `it`; up to min(rem, NBUF-2) tiles may stay in flight
        const int rem = NIT - 1 - it;
        const int allowed = (rem < NBUF - 2) ? rem : (NBUF - 2);
        if (allowed >= 2)      asm volatile("s_waitcnt vmcnt(8)" ::: "memory");
        else if (allowed == 1) asm volatile("s_waitcnt vmcnt(4)" ::: "memory");
        else                   asm volatile("s_waitcnt vmcnt(0)" ::: "memory");
        __builtin_amdgcn_s_barrier();
        if (it + NBUF - 1 < NIT) {
            const int nb = (it + NBUF - 1) % NBUF;
            gload_lds16(Ag,       As[nb] + tid * 8);
            gload_lds16(Ag + rsA, As[nb] + (256 + tid) * 8);
            gload_lds16(Bg,       Bs[nb] + tid * 8);
            gload_lds16(Bg + rsB, Bs[nb] + (256 + tid) * 8);
            Ag += 64; Bg += 64;
        }
        const ushort_t* Ab = As[it % NBUF];
        const ushort_t* Bb = Bs[it % NBUF];
#pragma unroll
        for (int kk = 0; kk < 2; ++kk) {
            short8 b0 = *(const short8*)(Bb + offB[kk][0]);
            short8 b1 = *(const short8*)(Bb + offB[kk][1]);
#pragma unroll
            for (int mi = 0; mi < 2; ++mi) {
                short8 a = *(const short8*)(Ab + offA[kk][mi]);
                acc[mi][0] = __builtin_amdgcn_mfma_f32_16x16x32_bf16(a, b0, acc[mi][0], 0, 0, 0);
                acc[mi][1] = __builtin_amdgcn_mfma_f32_16x16x32_bf16(a, b1, acc[mi][1], 0, 0, 0);
            }
        }
    }

    YT* yp = y + (size_t)ks * BD;
    const int mb = mt * 64 + waveM * 32 + q * 4;
    const int nb = bn + waveN * 32 + rl;
#pragma unroll
    for (int mi = 0; mi < 2; ++mi)
#pragma unroll
        for (int r = 0; r < 4; ++r) {
            yp[(size_t)(mb + mi * 16 + r) * DD + nb]      = (YT)acc[mi][0][r];
            yp[(size_t)(mb + mi * 16 + r) * DD + nb + 16] = (YT)acc[mi][1][r];
        }
}

// ---------------- step 0: c, g0 = tanh(c) (bf16 plane), Azz, state init ----------------
__global__ __launch_bounds__(512)
void epi0(const float* __restrict__ y, const float* __restrict__ bias,
          float* __restrict__ c, ushort_t* __restrict__ gxp,
          ushort_t* __restrict__ Azz, float* __restrict__ state,
          float* __restrict__ scal) {
    __shared__ float red[8];
    const int tid = threadIdx.x;
    const int b = blockIdx.x;
    const int col = tid * 4;
    const size_t base = (size_t)b * DD + col;

    float4 cc = *(const float4*)(bias + col);
#pragma unroll
    for (int s = 0; s < NKS0; ++s) {
        float4 v = *(const float4*)(y + (size_t)s * BD + base);
        cc.x += v.x; cc.y += v.y; cc.z += v.z; cc.w += v.w;
    }
    *(float4*)(c + base) = cc;
    float4 g = { fast_tanh(cc.x), fast_tanh(cc.y), fast_tanh(cc.z), fast_tanh(cc.w) };
    ushort4 gs = { f2bf(g.x), f2bf(g.y), f2bf(g.z), f2bf(g.w) };
    *(ushort4*)(gxp + base) = gs;
    *(ushort4*)(Azz + base) = gs;     // x1 = g0, single bf16 plane

    float pd = g.x*g.x + g.y*g.y + g.z*g.z + g.w*g.w;
    pd = wave_red(pd);
    if ((tid & 63) == 0) red[tid >> 6] = pd;
    __syncthreads();
    if (tid == 0) {
        float t = 0.f;
#pragma unroll
        for (int w2 = 0; w2 < 8; ++w2) t += red[w2];
        float* stb = state + (size_t)b * ST_SZ;
        stb[ST_S + 0]   = t;
        stb[ST_PHI + 0] = 1.f;
        stb[ST_XI + 0]  = 1.f;
        atomicAdd(&scal[0], t);
    }
}

// ---------------- Gram-space Broyden (bf16 g-planes, fp16 y) ----------------
// Solve is wave-0-synchronous: every stage uses lanes 0-63 only; in-wave
// lgkmcnt fences replace intermediate __syncthreads (3 full barriers total).
__global__ __launch_bounds__(512)
void broyden_gram(const half_t* __restrict__ yh, const float* __restrict__ c,
                  ushort_t* __restrict__ gxp, ushort_t* __restrict__ Azz,
                  float* __restrict__ state, float* __restrict__ scal, int k)
{
    __shared__ float red[8][16];
    __shared__ float dots[14];
    __shared__ float Sl[169], Al[156], Bl[156], PHl[13], XIl[13];
    __shared__ float newA[14], newB[14], nphi[14];
    __shared__ double dyv[13], dxtu[12], dvdg[12], dcgx[13], dden[1];
    const int tid = threadIdx.x;
    const int lane = tid & 63, w = tid >> 6;
    const int b = blockIdx.x;
    const int p = k - 1;
    float* stb = state + (size_t)b * ST_SZ;

    // vector loads first (long pole): G planes, y partials, c
    const int col = tid * 4;
    const size_t base = (size_t)b * DD + col;

    float4 G[12];
#pragma unroll
    for (int j = 0; j < 12; ++j)
        if (j < k) {
            ushort4 gu = *(const ushort4*)(gxp + (size_t)j * BD + base);
            G[j] = (float4){ bf2f(gu.x), bf2f(gu.y), bf2f(gu.z), bf2f(gu.w) };
        }

    float4 pre = *(const float4*)(c + base);
#pragma unroll
    for (int s = 0; s < NKSL; ++s) {
        half4 v = *(const half4*)(yh + (size_t)s * BD + base);
        pre.x += (float)v.x; pre.y += (float)v.y;
        pre.z += (float)v.z; pre.w += (float)v.w;
    }

    // LDS state staging
    for (int i = tid; i < 169; i += 512) Sl[i] = stb[ST_S + i];
    for (int i = tid; i < 156; i += 512) { Al[i] = stb[ST_A + i]; Bl[i] = stb[ST_B + i]; }
    if (tid < 13) { PHl[tid] = stb[ST_PHI + tid]; XIl[tid] = stb[ST_XI + tid]; }

    __syncthreads();

    float4 x = {0.f, 0.f, 0.f, 0.f};
#pragma unroll
    for (int j = 0; j < 12; ++j)
        if (j < k) {
            float xc = XIl[j];
            x.x = fmaf(xc, G[j].x, x.x); x.y = fmaf(xc, G[j].y, x.y);
            x.z = fmaf(xc, G[j].z, x.z); x.w = fmaf(xc, G[j].w, x.w);
        }
    float4 gk = { fast_tanh(pre.x) - x.x, fast_tanh(pre.y) - x.y,
                  fast_tanh(pre.z) - x.z, fast_tanh(pre.w) - x.w };

    // g_k plane store hoisted: independent of solve, overlaps reductions
    {
        ushort4 gs = { f2bf(gk.x), f2bf(gk.y), f2bf(gk.z), f2bf(gk.w) };
        *(ushort4*)(gxp + (size_t)k * BD + base) = gs;
    }

#pragma unroll
    for (int j = 0; j < 12; ++j)
        if (j < k) {
            float pd = G[j].x*gk.x + G[j].y*gk.y + G[j].z*gk.z + G[j].w*gk.w;
            pd = wave_red(pd);
            if (lane == 0) red[w][j] = pd;
        }
    {
        float pdk = gk.x*gk.x + gk.y*gk.y + gk.z*gk.z + gk.w*gk.w;
        pdk = wave_red(pdk);
        if (lane == 0) red[w][k] = pdk;
    }
    __syncthreads();

    if (w == 0) {
        if (lane <= k) {
            float s = 0.f;
#pragma unroll
            for (int w2 = 0; w2 < 8; ++w2) s += red[w2][lane];
            dots[lane] = s;
            if (lane == k) atomicAdd(&scal[k], s);
        }
        WS();
        // ---- scalar solve (fp64), wave-synchronous ----
        if (lane < k) {
            double s = 0.0;
            for (int j = 0; j < k; ++j) s += (double)Sl[lane*13 + j] * (double)PHl[j];
            dyv[lane] = s;
        }
        WS();
        if (lane < p) {
            double sx = 0.0, sv = 0.0;
            for (int j = 0; j < k; ++j) {
                sx += (double)Al[lane*13 + j] * dyv[j];
                sv += (double)Bl[lane*13 + j] * ((double)dots[j] - (double)Sl[j*13 + (k-1)]);
            }
            dxtu[lane] = sx; dvdg[lane] = sv;
        }
        WS();
        if (lane < k) {
            double s = -(double)PHl[lane];
            for (int t = 0; t < p; ++t) s += dxtu[t] * (double)Bl[t*13 + lane];
            newB[lane] = (float)s;
        }
        WS();
        if (lane == 0) {
            double s = 0.0;
            for (int j = 0; j < k; ++j)
                s += (double)newB[j] * ((double)dots[j] - (double)Sl[j*13 + (k-1)]);
            dden[0] = s;
        }
        if (lane >= 32 && lane < 32 + p) {
            int t = lane - 32;
            double s = 0.0;
            for (int j = 0; j < k; ++j) s += (double)Bl[t*13 + j] * (double)dots[j];
            dcgx[t] = s;
        }
        if (lane == 63) {
            double s = 0.0;
            for (int j = 0; j < k; ++j) s += (double)newB[j] * (double)dots[j];
            dcgx[p] = s;
        }
        WS();
        if (lane <= k) {
            double s = (double)((lane < 13) ? PHl[lane] : 0.f);
            if (lane == k)     s += 1.0;
            if (lane == k - 1) s -= 1.0;
            for (int t = 0; t < p; ++t) s -= dvdg[t] * (double)Al[t*13 + lane];
            newA[lane] = (float)(s / dden[0]);
        }
        WS();
        if (lane <= k) {
            double s = (lane == k) ? 1.0 : 0.0;
            for (int t = 0; t < p; ++t) s -= dcgx[t] * (double)Al[t*13 + lane];
            s -= dcgx[p] * (double)newA[lane];
            nphi[lane] = (float)s;
        }
        WS();
        // state writeback (wave 0)
        if (lane <= k) {
            stb[ST_S + k*13 + lane] = dots[lane];
            stb[ST_S + lane*13 + k] = dots[lane];
            stb[ST_A + p*13 + lane] = newA[lane];
            stb[ST_PHI + lane] = nphi[lane];
            float xi_old = (lane < 13) ? XIl[lane] : 0.f;
            stb[ST_XI + lane] = xi_old + nphi[lane];
        }
        if (lane < k) stb[ST_B + p*13 + lane] = newB[lane];
        if (lane < 13) stb[ST_XSN + k*13 + lane] = XIl[lane];   // coeffs of x_k
    }
    __syncthreads();

    if (k < TT) {   // x_{k+1}/Azz dead at k=TT
        float4 xn = x;
#pragma unroll
        for (int j = 0; j < 12; ++j)
            if (j < k) {
                float fc = nphi[j];
                xn.x = fmaf(fc, G[j].x, xn.x); xn.y = fmaf(fc, G[j].y, xn.y);
                xn.z = fmaf(fc, G[j].z, xn.z); xn.w = fmaf(fc, G[j].w, xn.w);
            }
        float fk = nphi[k];
        xn.x = fmaf(fk, gk.x, xn.x); xn.y = fmaf(fk, gk.y, xn.y);
        xn.z = fmaf(fk, gk.z, xn.z); xn.w = fmaf(fk, gk.w, xn.w);

        ushort4 h = { f2bf(xn.x), f2bf(xn.y), f2bf(xn.z), f2bf(xn.w) };
        *(ushort4*)(Azz + base) = h;              // single bf16 plane
    }
}

// ---------------- final: argmin obj; out = x_bk + g_bk from bf16 planes ----------------
__global__ __launch_bounds__(256)
void final_out(const ushort_t* __restrict__ gxp, const float* __restrict__ state,
               const float* __restrict__ scal, float* __restrict__ out) {
    const int i4 = blockIdx.x * 256 + threadIdx.x;
    float best = scal[0];
    int bk = 0;
#pragma unroll
    for (int k = 1; k <= TT; ++k) {
        float o = scal[k];
        if (o < best) { best = o; bk = k; }
    }
    const size_t idx = (size_t)i4 * 4;
    const int m = (int)(idx >> 11);
    const float* cf = state + (size_t)m * ST_SZ + ST_XSN + bk * 13;
    ushort4 gb = *(const ushort4*)(gxp + (size_t)bk * BD + idx);
    float4 r = { bf2f(gb.x), bf2f(gb.y), bf2f(gb.z), bf2f(gb.w) };
    for (int j = 0; j < bk; ++j) {
        float c1 = cf[j];
        ushort4 gu = *(const ushort4*)(gxp + (size_t)j * BD + idx);
        r.x = fmaf(c1, bf2f(gu.x), r.x); r.y = fmaf(c1, bf2f(gu.y), r.y);
        r.z = fmaf(c1, bf2f(gu.z), r.z); r.w = fmaf(c1, bf2f(gu.w), r.w);
    }
    ((float4*)out)[i4] = r;
}

// ---------------- launch ----------------
extern "C" void kernel_launch(void* const* d_in, const int* in_sizes, int n_in,
                              void* d_out, int out_size, void* d_ws, size_t ws_size,
                              hipStream_t stream) {
    const float* xin  = (const float*)d_in[0];
    const float* W    = (const float*)d_in[2];
    const float* U    = (const float*)d_in[3];
    const float* bias = (const float*)d_in[4];
    float* out = (float*)d_out;

    float* ws = (float*)d_ws;
    float* c      = ws;                                   // 1 BD
    float* y      = ws + 1 * (size_t)BD;                  // 8 BD fp32 (k0) / 4 fp16 planes (loop)
    ushort_t* gxp = (ushort_t*)(ws + 9 * (size_t)BD);     // 13 bf16 planes = 6.5 BD
    ushort_t* Axx = (ushort_t*)(ws + 16 * (size_t)BD);    // [256][4096] u16 = 1 BD
    ushort_t* Azz = (ushort_t*)(ws + 17 * (size_t)BD);    // [256][2048] u16 = 0.5 BD
    ushort_t* Wt  = (ushort_t*)(ws + 18 * (size_t)BD);    // 4 BD
    ushort_t* Ut  = (ushort_t*)(ws + 22 * (size_t)BD);    // 4 BD
    float* state  = ws + 26 * (size_t)BD;                 // 0.5 BD
    float* scal   = state + (size_t)BB * ST_SZ;           // 32 floats

    prep<<<2560, 256, 0, stream>>>(W, U, Wt, Ut, xin, Axx, state);

    // k=0: hi|lo A (K=4096), fp32 y, 8 k-slices, double-buffered, 4 blocks/CU
    dim3 gg0(32, 4, NKS0);   // 1024 blocks
    gemm_t<4096, 512, 8, 3, 2, float><<<gg0, 256, 0, stream>>>(Axx, Ut, y);
    epi0<<<BB, 512, 0, stream>>>(y, bias, c, gxp, Azz, state, scal);

    dim3 gg(32, 4, NKSL);    // 512 blocks (R16 config, quad-buffered)
    for (int k = 1; k <= TT; ++k) {
        // loop: single bf16 A (K=2048), fp16 y
        gemm_t<2048, 512, 8, 3, 4, half_t><<<gg, 256, 0, stream>>>(Azz, Wt, (half_t*)y);
        broyden_gram<<<BB, 512, 0, stream>>>((const half_t*)y, c, gxp, Azz, state, scal, k);
    }

    final_out<<<512, 256, 0, stream>>>(gxp, state, scal, out);
}